// Round 1
// baseline (52.824 us; speedup 1.0000x reference)
//
#include <hip/hip_runtime.h>

// Output of the reference forward pass is exactly the hard top-k0 mask (the
// straight-through (hard - soft) + soft == hard up to 1 ulp). The top-k0 set
// of soft == top-k0 set of x (clip is monotone; saturation ties at 1.0 are all
// selected, zeros all unselected, boundary is strictly ordered). Tie-break for
// exact fp32 duplicates: lowest index first (matches jax.lax.top_k).
//
// One block (256 threads) per row. Keys mapped to sortable uint32, staged in
// dynamic LDS. 4-pass MSB radix select finds the k-th largest key and the
// remaining rank kr within its tie group; mask = (key > t) | first-kr ties in
// index order (blocked distribution + exclusive scan gives index-order ranks).

__global__ void __launch_bounds__(256)
topk_mask_kernel(const float* __restrict__ x, const int* __restrict__ k0ptr,
                 float* __restrict__ out, int dim) {
    const int row = blockIdx.x;
    const int tid = threadIdx.x;
    const float* xr  = x   + (size_t)row * dim;
    float*       outr = out + (size_t)row * dim;

    extern __shared__ unsigned int su[];   // dim sortable keys
    __shared__ int hist[256];
    __shared__ int bcast[2];
    __shared__ int scanbuf[256];

    const int k = k0ptr[0];

    // Load row, map fp32 -> sortable-ascending uint32.
    for (int j = tid; j < dim; j += 256) {
        unsigned int b = __float_as_uint(xr[j]);
        su[j] = (b & 0x80000000u) ? ~b : (b | 0x80000000u);
    }
    __syncthreads();

    // MSB-first radix select: find key of k-th largest.
    unsigned int prefix = 0u, pmask = 0u;
    int kr = k;  // 1-based rank remaining among current candidates
    for (int shift = 24; shift >= 0; shift -= 8) {
        hist[tid] = 0;
        __syncthreads();
        for (int j = tid; j < dim; j += 256) {
            unsigned int u = su[j];
            if ((u & pmask) == prefix)
                atomicAdd(&hist[(u >> shift) & 255u], 1);
        }
        __syncthreads();
        if (tid == 0) {
            int cum = 0, chosen = 0;
            for (int b = 255; b >= 0; --b) {
                int h = hist[b];
                if (cum + h >= kr) { chosen = b; break; }
                cum += h;
            }
            bcast[0] = cum;
            bcast[1] = chosen;
        }
        __syncthreads();
        kr -= bcast[0];
        prefix |= ((unsigned int)bcast[1]) << shift;
        pmask  |= (0xFFu << shift);
        __syncthreads();   // hist reused next pass
    }
    // prefix = key of k-th largest; kr = how many ties (== prefix) to select.

    // Blocked distribution for index-ordered tie ranking.
    const int epb = (dim + 255) / 256;          // elements per thread
    const int lo = tid * epb;
    const int hi = (lo + epb < dim) ? (lo + epb) : dim;

    int eq = 0;
    for (int j = lo; j < hi; ++j) eq += (su[j] == prefix) ? 1 : 0;
    scanbuf[tid] = eq;
    __syncthreads();
    if (tid == 0) {                              // serial exclusive scan (256)
        int acc = 0;
        for (int i = 0; i < 256; ++i) { int v = scanbuf[i]; scanbuf[i] = acc; acc += v; }
    }
    __syncthreads();

    int rank = scanbuf[tid];
    for (int j = lo; j < hi; ++j) {
        unsigned int u = su[j];
        float o;
        if (u > prefix)       o = 1.0f;
        else if (u == prefix) { o = (rank < kr) ? 1.0f : 0.0f; ++rank; }
        else                  o = 0.0f;
        outr[j] = o;
    }
}

extern "C" void kernel_launch(void* const* d_in, const int* in_sizes, int n_in,
                              void* d_out, int out_size, void* d_ws, size_t ws_size,
                              hipStream_t stream) {
    const float* x    = (const float*)d_in[0];
    // d_in[1] = k vector [bs] (unused: selection count is k0; projection's nu
    // does not affect the hard mask — see header comment)
    const int*   k0   = (const int*)d_in[2];
    float*       out  = (float*)d_out;

    const int bs  = in_sizes[1];
    const int dim = in_sizes[0] / bs;
    const size_t smem = (size_t)dim * sizeof(unsigned int);

    topk_mask_kernel<<<bs, 256, smem, stream>>>(x, k0, out, dim);
}

// Round 2
// 16.933 us; speedup vs baseline: 3.1196x; 3.1196x over previous
//
#include <hip/hip_runtime.h>

// Forward output of the reference == hard top-k0 binary mask (straight-through
// (hard-soft)+soft == hard exactly in fp32; top-k0 of soft == top-k0 of x since
// clip(x+nu) is monotone, saturated 1.0-ties are all selected, 0-ties all
// unselected). Tie-break for exact fp32 duplicates: lowest index first
// (matches jax.lax.top_k).
//
// One block (256 thr) per row; dim=4096 keys -> sortable uint32 in LDS.
// 4-pass MSB radix select, FULLY PARALLEL selection:
//   - histogram: LDS atomics (pass 0 fused into the float4 load)
//   - 256-bin suffix-sum: per-wave shfl_down suffix scan + 4-way combine
//   - bin choice: ballot/popcount of the monotone predicate S[b] >= kr
// Common case kr==T (all ties of the threshold selected) -> conflict-free
// interleaved mask write; generic tie-ranking path uses wave prefix scans.

__global__ void __launch_bounds__(256)
topk_mask_kernel(const float* __restrict__ x, const int* __restrict__ k0ptr,
                 float* __restrict__ out, int dim) {
    const int row  = blockIdx.x;
    const int tid  = threadIdx.x;
    const int lane = tid & 63;
    const int wave = tid >> 6;
    const float* xr   = x   + (size_t)row * dim;
    float*       outr = out + (size_t)row * dim;

    extern __shared__ unsigned int su[];   // dim sortable keys
    __shared__ int hist[256];
    __shared__ int SS[256];                // suffix sums
    __shared__ int wtot[4];
    __shared__ int cnt[4];

    int kr = k0ptr[0];                     // remaining rank (1-based)

    hist[tid] = 0;
    __syncthreads();

    // Vectorized load + sortable map + fused pass-0 histogram (top byte).
    const float4* xr4 = (const float4*)xr;
    const int dim4 = dim >> 2;
    for (int i = tid; i < dim4; i += 256) {
        float4 v = xr4[i];
        unsigned int b0 = __float_as_uint(v.x);
        unsigned int b1 = __float_as_uint(v.y);
        unsigned int b2 = __float_as_uint(v.z);
        unsigned int b3 = __float_as_uint(v.w);
        unsigned int u0 = (b0 & 0x80000000u) ? ~b0 : (b0 | 0x80000000u);
        unsigned int u1 = (b1 & 0x80000000u) ? ~b1 : (b1 | 0x80000000u);
        unsigned int u2 = (b2 & 0x80000000u) ? ~b2 : (b2 | 0x80000000u);
        unsigned int u3 = (b3 & 0x80000000u) ? ~b3 : (b3 | 0x80000000u);
        const int j = i << 2;
        su[j + 0] = u0; su[j + 1] = u1; su[j + 2] = u2; su[j + 3] = u3;
        atomicAdd(&hist[u0 >> 24], 1);
        atomicAdd(&hist[u1 >> 24], 1);
        atomicAdd(&hist[u2 >> 24], 1);
        atomicAdd(&hist[u3 >> 24], 1);
    }
    __syncthreads();

    unsigned int prefix = 0u, pmask = 0u;
    int T = 0;                             // tie count at final pass
    for (int shift = 24; ; shift -= 8) {
        // ---- parallel suffix-sum of hist + bin selection ----
        const int h = hist[tid];
        int v = h;
        #pragma unroll
        for (int off = 1; off < 64; off <<= 1) {
            int t = __shfl_down(v, off, 64);
            if (lane + off < 64) v += t;
        }                                   // v = suffix sum within wave
        if (lane == 0) wtot[wave] = v;      // wave total
        __syncthreads();
        int add = 0;
        #pragma unroll
        for (int w = 0; w < 4; ++w) if (w > wave) add += wtot[w];
        v += add;                           // S[tid] = sum of hist[tid..255]
        SS[tid] = v;
        const unsigned long long m = __ballot(v >= kr);   // monotone in tid
        if (lane == 0) cnt[wave] = __popcll(m);
        __syncthreads();
        const int chosen = cnt[0] + cnt[1] + cnt[2] + cnt[3] - 1;
        const int cumG = (chosen < 255) ? SS[chosen + 1] : 0;  // strictly greater
        T = hist[chosen];
        kr -= cumG;
        prefix |= ((unsigned int)chosen) << shift;
        pmask  |= 0xFFu << shift;
        if (shift == 0) break;

        // ---- rebuild histogram for next byte among surviving candidates ----
        __syncthreads();
        hist[tid] = 0;
        __syncthreads();
        const int ns = shift - 8;
        for (int j = tid; j < dim; j += 256) {
            const unsigned int u = su[j];
            if ((u & pmask) == prefix)
                atomicAdd(&hist[(u >> ns) & 255u], 1);
        }
        __syncthreads();
    }
    // prefix = key of k-th largest; kr = ties to select; T = total ties.

    if (kr == T) {
        // All ties selected: pure threshold mask, interleaved = conflict-free
        // LDS reads + coalesced global stores.
        for (int j = tid; j < dim; j += 256)
            outr[j] = (su[j] >= prefix) ? 1.0f : 0.0f;
    } else {
        // Rare path: rank ties in index order (blocked distribution + wave
        // prefix scans over per-thread tie counts).
        const int epb = dim >> 8;          // 16 for dim=4096
        const int lo = tid * epb, hi = lo + epb;
        int eq = 0;
        for (int j = lo; j < hi; ++j) eq += (su[j] == prefix) ? 1 : 0;
        int v = eq;
        #pragma unroll
        for (int off = 1; off < 64; off <<= 1) {
            int t = __shfl_up(v, off, 64);
            if (lane >= off) v += t;
        }                                   // inclusive prefix within wave
        __syncthreads();                    // protect wtot reuse
        if (lane == 63) wtot[wave] = v;
        __syncthreads();
        int offv = 0;
        for (int w = 0; w < wave; ++w) offv += wtot[w];
        int rank = (v - eq) + offv;         // exclusive prefix, index order
        for (int j = lo; j < hi; ++j) {
            const unsigned int u = su[j];
            float o;
            if (u > prefix)       o = 1.0f;
            else if (u == prefix) { o = (rank < kr) ? 1.0f : 0.0f; ++rank; }
            else                  o = 0.0f;
            outr[j] = o;
        }
    }
}

extern "C" void kernel_launch(void* const* d_in, const int* in_sizes, int n_in,
                              void* d_out, int out_size, void* d_ws, size_t ws_size,
                              hipStream_t stream) {
    const float* x   = (const float*)d_in[0];
    // d_in[1] = k vector [bs] (unused: forward mask depends only on k0)
    const int*   k0  = (const int*)d_in[2];
    float*       out = (float*)d_out;

    const int bs  = in_sizes[1];
    const int dim = in_sizes[0] / bs;      // 4096 (multiple of 256 assumed)
    const size_t smem = (size_t)dim * sizeof(unsigned int);

    topk_mask_kernel<<<bs, 256, smem, stream>>>(x, k0, out, dim);
}

// Round 3
// 16.910 us; speedup vs baseline: 3.1239x; 1.0014x over previous
//
#include <hip/hip_runtime.h>

// Forward output of the reference == hard top-k0 binary mask (straight-through
// (hard-soft)+soft == hard exactly in fp32; top-k0 set of soft == top-k0 set
// of x since clip(x+nu) is monotone). Tie-break for exact fp32 duplicates:
// lowest index first (matches jax.lax.top_k).
//
// BARRIER-FREE design: one 64-lane wave per row (dim=4096 -> 64 keys/lane in
// REGISTERS, all loops fully unrolled so indexing is static). Only LDS object
// is a wave-private 256-bin histogram -> no __syncthreads at all; same-wave DS
// ordering + s_waitcnt lgkmcnt(0) is sufficient.
//
// 4-pass MSB radix select per wave:
//   hist: 64 predicated ds_atomic_add per lane (survivor-filtered after p0)
//   suffix-sum: ds_read_b128 (4 bins/lane) + 3 local adds + 6-shfl wave scan
//   bin pick: unique bracket lane via __ballot, 3 shfl broadcasts

#define DIM 4096
#define EPL 64   // elements per lane

__global__ void __launch_bounds__(64)
topk_mask_kernel(const float* __restrict__ x, const int* __restrict__ k0ptr,
                 float* __restrict__ out) {
    const int row  = blockIdx.x;
    const int lane = threadIdx.x;

    const float4* xr4   = (const float4*)(x   + (size_t)row * DIM);
    float4*       outr4 = (float4*)      (out + (size_t)row * DIM);

    __shared__ int hist[256];

    hist[lane]       = 0;
    hist[lane + 64]  = 0;
    hist[lane + 128] = 0;
    hist[lane + 192] = 0;
    asm volatile("s_waitcnt lgkmcnt(0)" ::: "memory");

    // ---- load (coalesced float4), map to sortable uint, pass-0 histogram ----
    unsigned int u[EPL];
    #pragma unroll
    for (int i = 0; i < 16; ++i) {
        const float4 v = xr4[lane + (i << 6)];
        unsigned int b0 = __float_as_uint(v.x);
        unsigned int b1 = __float_as_uint(v.y);
        unsigned int b2 = __float_as_uint(v.z);
        unsigned int b3 = __float_as_uint(v.w);
        u[4*i+0] = (b0 & 0x80000000u) ? ~b0 : (b0 | 0x80000000u);
        u[4*i+1] = (b1 & 0x80000000u) ? ~b1 : (b1 | 0x80000000u);
        u[4*i+2] = (b2 & 0x80000000u) ? ~b2 : (b2 | 0x80000000u);
        u[4*i+3] = (b3 & 0x80000000u) ? ~b3 : (b3 | 0x80000000u);
        atomicAdd(&hist[u[4*i+0] >> 24], 1);
        atomicAdd(&hist[u[4*i+1] >> 24], 1);
        atomicAdd(&hist[u[4*i+2] >> 24], 1);
        atomicAdd(&hist[u[4*i+3] >> 24], 1);
    }

    int kr = k0ptr[0];                 // remaining 1-based rank
    unsigned int prefix = 0u, pmask = 0u;
    int T = 0;                         // tie count of threshold key

    #pragma unroll
    for (int pass = 0; pass < 4; ++pass) {
        const int shift = 24 - 8 * pass;
        asm volatile("s_waitcnt lgkmcnt(0)" ::: "memory");  // hist complete
        const int4 h = *(const int4*)&hist[lane << 2];      // bins 4l..4l+3

        // in-lane suffix sums, then wave suffix scan of lane totals
        const int s3 = h.w;
        const int s2 = h.z + s3;
        const int s1 = h.y + s2;
        const int s0 = h.x + s1;
        int v = s0;
        #pragma unroll
        for (int off = 1; off < 64; off <<= 1) {
            int t = __shfl_down(v, off, 64);
            if (lane + off < 64) v += t;
        }
        const int inc = v - s0;        // sum of totals of lanes > l
        const int S0 = s0 + inc, S1 = s1 + inc, S2 = s2 + inc, S3 = s3 + inc;

        int ci, cumG, Tl;
        if      (S3 >= kr) { ci = 3; cumG = inc; Tl = h.w; }
        else if (S2 >= kr) { ci = 2; cumG = S3;  Tl = h.z; }
        else if (S1 >= kr) { ci = 1; cumG = S2;  Tl = h.y; }
        else               { ci = 0; cumG = S1;  Tl = h.x; }

        const bool has = (S0 >= kr) && (inc < kr);   // exactly one lane
        const unsigned long long m = __ballot(has);
        const int src = __ffsll(m) - 1;

        const int chosen = __shfl((lane << 2) + ci, src, 64);
        cumG = __shfl(cumG, src, 64);
        T    = __shfl(Tl,   src, 64);

        kr -= cumG;
        prefix |= ((unsigned int)chosen) << shift;
        pmask  |= 0xFFu << shift;

        if (pass < 3) {
            // zero (after the b128 read completed) + rebuild among survivors
            hist[lane]       = 0;
            hist[lane + 64]  = 0;
            hist[lane + 128] = 0;
            hist[lane + 192] = 0;
            asm volatile("s_waitcnt lgkmcnt(0)" ::: "memory");
            const int ns = shift - 8;
            #pragma unroll
            for (int j = 0; j < EPL; ++j) {
                if ((u[j] & pmask) == prefix)
                    atomicAdd(&hist[(u[j] >> ns) & 255u], 1);
            }
        }
    }
    // prefix = k-th largest key; kr = ties to select; T = total ties.

    if (kr == T) {
        // All threshold ties selected: pure >= mask from registers.
        #pragma unroll
        for (int i = 0; i < 16; ++i) {
            float4 o;
            o.x = (u[4*i+0] >= prefix) ? 1.0f : 0.0f;
            o.y = (u[4*i+1] >= prefix) ? 1.0f : 0.0f;
            o.z = (u[4*i+2] >= prefix) ? 1.0f : 0.0f;
            o.w = (u[4*i+3] >= prefix) ? 1.0f : 0.0f;
            outr4[lane + (i << 6)] = o;
        }
    } else {
        // Rare: rank ties in global index order. Element index of u[4i+c] is
        // 256*i + 4*lane + c -> lexicographic (i, lane, c).
        int base = 0;
        #pragma unroll
        for (int i = 0; i < 16; ++i) {
            const int e0 = (u[4*i+0] == prefix);
            const int e1 = (u[4*i+1] == prefix);
            const int e2 = (u[4*i+2] == prefix);
            const int e3 = (u[4*i+3] == prefix);
            const int ti = e0 + e1 + e2 + e3;
            int v = ti;
            #pragma unroll
            for (int off = 1; off < 64; off <<= 1) {
                int t = __shfl_up(v, off, 64);
                if (lane >= off) v += t;
            }
            int r = base + (v - ti);           // my first tie's rank
            const int tot = __shfl(v, 63, 64); // ties in this i across wave
            float4 o;
            o.x = (u[4*i+0] > prefix) ? 1.0f : (e0 && r < kr) ? 1.0f : 0.0f; r += e0;
            o.y = (u[4*i+1] > prefix) ? 1.0f : (e1 && r < kr) ? 1.0f : 0.0f; r += e1;
            o.z = (u[4*i+2] > prefix) ? 1.0f : (e2 && r < kr) ? 1.0f : 0.0f; r += e2;
            o.w = (u[4*i+3] > prefix) ? 1.0f : (e3 && r < kr) ? 1.0f : 0.0f; r += e3;
            outr4[lane + (i << 6)] = o;
            base += tot;
        }
    }
}

extern "C" void kernel_launch(void* const* d_in, const int* in_sizes, int n_in,
                              void* d_out, int out_size, void* d_ws, size_t ws_size,
                              hipStream_t stream) {
    const float* x   = (const float*)d_in[0];
    // d_in[1] = k vector [bs] (unused: forward mask depends only on k0)
    const int*   k0  = (const int*)d_in[2];
    float*       out = (float*)d_out;

    const int bs = in_sizes[1];        // dim == 4096 (reference setup)
    topk_mask_kernel<<<bs, 64, 0, stream>>>(x, k0, out);
}

// Round 4
// 12.450 us; speedup vs baseline: 4.2430x; 1.3582x over previous
//
#include <hip/hip_runtime.h>

// Forward output of the reference == hard top-k0 binary mask (straight-through
// (hard-soft)+soft == hard exactly in fp32; top-k0 set of soft == top-k0 set
// of x since clip(x+nu) is monotone). Tie-break for exact fp32 duplicates:
// lowest index first (matches jax.lax.top_k).
//
// One 256-thread block (4 waves) per row; 16 keys/lane in REGISTERS.
// 4-pass MSB radix select. Histogram pass 0 is the hot spot: sortable-uint top
// byte is sign|exp[7:1], so ~29% of normal data shares ONE byte -> LDS atomic
// same-address serialization dominated earlier rounds. Fix: 16 replicated
// histogram copies (copy = 4*wave + (lane&3), stride 260 ints = 16B-aligned,
// bank-shifted). Passes 1-3 hit few survivors -> single-copy regions, all
// zeroed once up front. 5 barriers total.

#define DIM   4096
#define EPL   16            // elems per lane (4 waves * 64 lanes * 16 = 4096)
#define NC0   16            // pass-0 histogram copies
#define CPAD  260           // copy stride in ints (1040 B: 16B-aligned, bank-shifted)

__global__ void __launch_bounds__(256)
topk_mask_kernel(const float* __restrict__ x, const int* __restrict__ k0ptr,
                 float* __restrict__ out) {
    const int tid  = threadIdx.x;
    const int lane = tid & 63;
    const int w    = tid >> 6;
    const int row  = blockIdx.x;

    const float4* xr4   = (const float4*)(x   + (size_t)row * DIM);
    float4*       outr4 = (float4*)      (out + (size_t)row * DIM);

    __shared__ int hist0[NC0 * CPAD];   // pass-0 replicated histograms
    __shared__ int histp[3][256];       // passes 1..3 (few survivors)
    __shared__ int wtie[4];

    // Issue global loads first; latency hides under LDS zeroing.
    // Wave w owns floats [1024w, 1024w+1024); elem (i,lane,c) -> index
    // 1024w + 256i + 4*lane + c (lexicographic (i,lane,c) = ascending index).
    const float4 f0 = xr4[(w << 8) + lane];
    const float4 f1 = xr4[(w << 8) + 64  + lane];
    const float4 f2 = xr4[(w << 8) + 128 + lane];
    const float4 f3 = xr4[(w << 8) + 192 + lane];

    for (int t = tid; t < NC0 * CPAD; t += 256) hist0[t] = 0;
    for (int t = tid; t < 3 * 256;   t += 256) ((int*)histp)[t] = 0;

    // Map fp32 -> sortable-ascending uint32 (registers, static indexing).
    unsigned int u[EPL];
#define MAP4(i, vv)                                                        \
    {                                                                      \
        unsigned int b0 = __float_as_uint((vv).x);                         \
        unsigned int b1 = __float_as_uint((vv).y);                         \
        unsigned int b2 = __float_as_uint((vv).z);                         \
        unsigned int b3 = __float_as_uint((vv).w);                         \
        u[4*(i)+0] = (b0 & 0x80000000u) ? ~b0 : (b0 | 0x80000000u);        \
        u[4*(i)+1] = (b1 & 0x80000000u) ? ~b1 : (b1 | 0x80000000u);        \
        u[4*(i)+2] = (b2 & 0x80000000u) ? ~b2 : (b2 | 0x80000000u);        \
        u[4*(i)+3] = (b3 & 0x80000000u) ? ~b3 : (b3 | 0x80000000u);        \
    }
    MAP4(0, f0) MAP4(1, f1) MAP4(2, f2) MAP4(3, f3)
#undef MAP4

    __syncthreads();   // zeros visible everywhere

    // Pass-0 histogram into this thread's replica.
    const int c0 = ((w << 2) | (lane & 3)) * CPAD;
    #pragma unroll
    for (int j = 0; j < EPL; ++j)
        atomicAdd(&hist0[c0 + (u[j] >> 24)], 1);
    __syncthreads();   // all replicas complete

    int kr = k0ptr[0];                 // remaining 1-based rank
    unsigned int prefix = 0u, pmask = 0u;
    int T = 0;                         // tie count of threshold key

    #pragma unroll
    for (int pass = 0; pass < 4; ++pass) {
        const int shift = 24 - 8 * pass;

        // ---- gather this lane's 4 bins (merged across replicas for pass 0) --
        int4 h;
        if (pass == 0) {
            h.x = 0; h.y = 0; h.z = 0; h.w = 0;
            #pragma unroll
            for (int c = 0; c < NC0; ++c) {
                const int4 t = *(const int4*)&hist0[c * CPAD + (lane << 2)];
                h.x += t.x; h.y += t.y; h.z += t.z; h.w += t.w;
            }
        } else {
            h = *(const int4*)&histp[pass - 1][lane << 2];
        }

        // ---- in-lane suffix sums + wave suffix scan of lane totals ----------
        const int s3 = h.w, s2 = h.z + s3, s1 = h.y + s2, s0 = h.x + s1;
        int v = s0;
        #pragma unroll
        for (int off = 1; off < 64; off <<= 1) {
            int t = __shfl_down(v, off, 64);
            if (lane + off < 64) v += t;
        }
        const int inc = v - s0;                  // totals of lanes > l
        const int S0 = s0 + inc, S1 = s1 + inc, S2 = s2 + inc, S3 = s3 + inc;

        int ci, cumG, Tl;
        if      (S3 >= kr) { ci = 3; cumG = inc; Tl = h.w; }
        else if (S2 >= kr) { ci = 2; cumG = S3;  Tl = h.z; }
        else if (S1 >= kr) { ci = 1; cumG = S2;  Tl = h.y; }
        else               { ci = 0; cumG = S1;  Tl = h.x; }

        const bool has = (S0 >= kr) && (inc < kr);   // exactly one lane true
        const unsigned long long m = __ballot(has);
        const int src = __ffsll(m) - 1;

        const int chosen = __shfl((lane << 2) + ci, src, 64);
        cumG = __shfl(cumG, src, 64);
        T    = __shfl(Tl,   src, 64);

        kr -= cumG;
        prefix |= ((unsigned int)chosen) << shift;
        pmask  |= 0xFFu << shift;

        if (pass < 3) {
            // rebuild next-byte histogram among survivors (sparse, uniform)
            const int ns = shift - 8;
            #pragma unroll
            for (int j = 0; j < EPL; ++j)
                if ((u[j] & pmask) == prefix)
                    atomicAdd(&histp[pass][(u[j] >> ns) & 255u], 1);
            __syncthreads();
        }
    }
    // prefix = k-th largest key; kr = ties to select; T = total ties.
    // kr,T identical across all threads -> branches below are block-uniform.

    if (kr == T) {
        // All threshold ties selected: pure >= mask from registers.
        #pragma unroll
        for (int i = 0; i < 4; ++i) {
            float4 o;
            o.x = (u[4*i+0] >= prefix) ? 1.0f : 0.0f;
            o.y = (u[4*i+1] >= prefix) ? 1.0f : 0.0f;
            o.z = (u[4*i+2] >= prefix) ? 1.0f : 0.0f;
            o.w = (u[4*i+3] >= prefix) ? 1.0f : 0.0f;
            outr4[(w << 8) + (i << 6) + lane] = o;
        }
    } else {
        // Rare: rank ties in ascending global index order.
        int eqtot = 0;
        #pragma unroll
        for (int j = 0; j < EPL; ++j) eqtot += (u[j] == prefix) ? 1 : 0;
        int vv = eqtot;
        #pragma unroll
        for (int off = 1; off < 64; off <<= 1) {
            int t = __shfl_up(vv, off, 64);
            if (lane >= off) vv += t;
        }
        if (lane == 63) wtie[w] = vv;            // wave tie totals
        __syncthreads();
        int base = 0;
        #pragma unroll
        for (int ww = 0; ww < 4; ++ww) if (ww < w) base += wtie[ww];

        #pragma unroll
        for (int i = 0; i < 4; ++i) {
            const int e0 = (u[4*i+0] == prefix) ? 1 : 0;
            const int e1 = (u[4*i+1] == prefix) ? 1 : 0;
            const int e2 = (u[4*i+2] == prefix) ? 1 : 0;
            const int e3 = (u[4*i+3] == prefix) ? 1 : 0;
            const int ti = e0 + e1 + e2 + e3;
            int vi = ti;
            #pragma unroll
            for (int off = 1; off < 64; off <<= 1) {
                int t = __shfl_up(vi, off, 64);
                if (lane >= off) vi += t;
            }
            int r = base + (vi - ti);            // ties before my first one
            const int tot = __shfl(vi, 63, 64);  // ties in this i-block
            float4 o;
            o.x = (u[4*i+0] > prefix) ? 1.0f : ((e0 && r < kr) ? 1.0f : 0.0f); r += e0;
            o.y = (u[4*i+1] > prefix) ? 1.0f : ((e1 && r < kr) ? 1.0f : 0.0f); r += e1;
            o.z = (u[4*i+2] > prefix) ? 1.0f : ((e2 && r < kr) ? 1.0f : 0.0f); r += e2;
            o.w = (u[4*i+3] > prefix) ? 1.0f : ((e3 && r < kr) ? 1.0f : 0.0f); r += e3;
            outr4[(w << 8) + (i << 6) + lane] = o;
            base += tot;
        }
    }
}

extern "C" void kernel_launch(void* const* d_in, const int* in_sizes, int n_in,
                              void* d_out, int out_size, void* d_ws, size_t ws_size,
                              hipStream_t stream) {
    const float* x   = (const float*)d_in[0];
    // d_in[1] = k vector [bs] (unused: forward mask depends only on k0)
    const int*   k0  = (const int*)d_in[2];
    float*       out = (float*)d_out;

    const int bs = in_sizes[1];        // dim == 4096 (reference setup)
    topk_mask_kernel<<<bs, 256, 0, stream>>>(x, k0, out);
}

// Round 5
// 11.948 us; speedup vs baseline: 4.4213x; 1.0420x over previous
//
#include <hip/hip_runtime.h>

// Forward output of the reference == hard top-k0 binary mask (straight-through
// (hard-soft)+soft == hard exactly in fp32; top-k0 set of soft == top-k0 set
// of x since clip(x+nu) is monotone). Tie-break for exact fp32 duplicates:
// lowest index first (matches jax.lax.top_k).
//
// One 512-thread block (8 waves) per row; 8 keys/lane in registers.
// Radix select: 2 histogram passes (8 bits each) fix the top-16-bit prefix;
// survivors (T ~ 4 for random data) are compacted and finished with a 16-step
// ballot bit-select. Histogram fallback for adversarial T > 64 keeps it exact.
// Pass-0 histogram uses 16 replicated copies (hot byte bin holds ~29% of
// normal data -> same-address LDS atomic serialization without replication).

#define DIM  4096
#define EPL  8              // elems per lane: 8 waves * 64 lanes * 8 = 4096
#define NC0  16             // pass-0 histogram replicas
#define CPAD 260            // replica stride (ints): 16B-aligned, bank-shifted

__device__ __forceinline__ void select_bin(const int4 h, const int lane, const int kr,
                                           int& chosen, int& cumG, int& T) {
    // h = this lane's 4 bins (bins 4*lane .. 4*lane+3). Finds bin containing
    // the kr-th largest, count strictly greater (cumG), and bin count (T).
    const int s3 = h.w, s2 = h.z + s3, s1 = h.y + s2, s0 = h.x + s1;
    int v = s0;
    #pragma unroll
    for (int off = 1; off < 64; off <<= 1) {
        int t = __shfl_down(v, off, 64);
        if (lane + off < 64) v += t;
    }
    const int inc = v - s0;                       // totals of lanes > l
    const int S0 = s0 + inc, S1 = s1 + inc, S2 = s2 + inc, S3 = s3 + inc;
    int ci, cg, Tl;
    if      (S3 >= kr) { ci = 3; cg = inc; Tl = h.w; }
    else if (S2 >= kr) { ci = 2; cg = S3;  Tl = h.z; }
    else if (S1 >= kr) { ci = 1; cg = S2;  Tl = h.y; }
    else               { ci = 0; cg = S1;  Tl = h.x; }
    const bool has = (S0 >= kr) && (inc < kr);    // exactly one lane true
    const unsigned long long m = __ballot(has);
    const int src = __ffsll((unsigned long long)m) - 1;
    chosen = __shfl((lane << 2) + ci, src, 64);
    cumG   = __shfl(cg, src, 64);
    T      = __shfl(Tl, src, 64);
}

__global__ void __launch_bounds__(512)
topk_mask_kernel(const float* __restrict__ x, const int* __restrict__ k0ptr,
                 float* __restrict__ out) {
    const int tid  = threadIdx.x;
    const int lane = tid & 63;
    const int w    = tid >> 6;                    // 0..7
    const int row  = blockIdx.x;

    const float4* xr4   = (const float4*)(x   + (size_t)row * DIM);
    float4*       outr4 = (float4*)      (out + (size_t)row * DIM);

    __shared__ int hist0[NC0 * CPAD];             // pass-0 replicas
    __shared__ int histp[3][256];                 // pass 1 + fallback passes
    __shared__ unsigned int surv[64];
    __shared__ int scnt;
    __shared__ int wtie[8];

    const int k0 = k0ptr[0];                      // early uniform load

    // Wave w owns elements [512w, 512w+512); elem of u[4i+c] (i in 0..1) is
    // 512w + 256i + 4*lane + c -> lexicographic (w,i,lane,c) = ascending idx.
    const float4 f0 = xr4[(w << 7) + lane];
    const float4 f1 = xr4[(w << 7) + 64 + lane];

    // Zero LDS while loads are in flight.
    for (int t = tid; t < NC0 * CPAD; t += 512) hist0[t] = 0;
    for (int t = tid; t < 3 * 256;   t += 512) ((int*)histp)[t] = 0;
    if (tid == 0) scnt = 0;

    // fp32 -> sortable-ascending uint32 (registers, static indexing).
    unsigned int u[EPL];
#define MAP4(i, vv)                                                        \
    {                                                                      \
        unsigned int b0 = __float_as_uint((vv).x);                         \
        unsigned int b1 = __float_as_uint((vv).y);                         \
        unsigned int b2 = __float_as_uint((vv).z);                         \
        unsigned int b3 = __float_as_uint((vv).w);                         \
        u[4*(i)+0] = (b0 & 0x80000000u) ? ~b0 : (b0 | 0x80000000u);        \
        u[4*(i)+1] = (b1 & 0x80000000u) ? ~b1 : (b1 | 0x80000000u);        \
        u[4*(i)+2] = (b2 & 0x80000000u) ? ~b2 : (b2 | 0x80000000u);        \
        u[4*(i)+3] = (b3 & 0x80000000u) ? ~b3 : (b3 | 0x80000000u);        \
    }
    MAP4(0, f0) MAP4(1, f1)
#undef MAP4

    __syncthreads();                              // zeros visible

    // ---- pass 0: replicated histogram of top byte ----
    const int c0 = ((((w & 1) << 3) | (lane & 7))) * CPAD;
    #pragma unroll
    for (int j = 0; j < EPL; ++j)
        atomicAdd(&hist0[c0 + (u[j] >> 24)], 1);
    __syncthreads();

    int kr = k0;
    int4 h; h.x = 0; h.y = 0; h.z = 0; h.w = 0;
    #pragma unroll
    for (int c = 0; c < NC0; ++c) {
        const int4 t = *(const int4*)&hist0[c * CPAD + (lane << 2)];
        h.x += t.x; h.y += t.y; h.z += t.z; h.w += t.w;
    }
    int chosen, cumG, T;
    select_bin(h, lane, kr, chosen, cumG, T);
    kr -= cumG;
    unsigned int pfx = ((unsigned int)chosen) << 24;

    // ---- pass 1: byte 2 among survivors (sparse -> single copy) ----
    #pragma unroll
    for (int j = 0; j < EPL; ++j)
        if ((u[j] >> 24) == (pfx >> 24))
            atomicAdd(&histp[0][(u[j] >> 16) & 255u], 1);
    __syncthreads();
    h = *(const int4*)&histp[0][lane << 2];
    select_bin(h, lane, kr, chosen, cumG, T);
    kr -= cumG;
    pfx |= ((unsigned int)chosen) << 16;

    unsigned int thr;
    if (T <= 64) {
        // ---- common path: compact survivors, ballot bit-select low 16 bits --
        #pragma unroll
        for (int j = 0; j < EPL; ++j)
            if ((u[j] & 0xFFFF0000u) == pfx) {
                const int slot = atomicAdd(&scnt, 1);
                surv[slot] = u[j];
            }
        __syncthreads();
        // Every wave runs this redundantly on identical data -> no broadcast.
        const unsigned int v = (lane < T) ? surv[lane] : 0u;
        bool act = (lane < T);
        #pragma unroll
        for (int b = 15; b >= 0; --b) {
            const unsigned int bit = (v >> b) & 1u;
            const unsigned long long m1 = __ballot(act && (bit != 0u));
            const int c = __popcll(m1);
            const bool ge = (c >= kr);
            act = act && (bit == (ge ? 1u : 0u));
            if (!ge) kr -= c;
        }
        const unsigned long long ma = __ballot(act);
        T   = __popcll(ma);
        thr = __shfl(v, __ffsll((unsigned long long)ma) - 1, 64);
    } else {
        // ---- fallback: histogram passes for bytes 1 and 0 ----
        #pragma unroll
        for (int j = 0; j < EPL; ++j)
            if ((u[j] & 0xFFFF0000u) == pfx)
                atomicAdd(&histp[1][(u[j] >> 8) & 255u], 1);
        __syncthreads();
        h = *(const int4*)&histp[1][lane << 2];
        select_bin(h, lane, kr, chosen, cumG, T);
        kr -= cumG;
        pfx |= ((unsigned int)chosen) << 8;

        #pragma unroll
        for (int j = 0; j < EPL; ++j)
            if ((u[j] & 0xFFFFFF00u) == pfx)
                atomicAdd(&histp[2][u[j] & 255u], 1);
        __syncthreads();
        h = *(const int4*)&histp[2][lane << 2];
        select_bin(h, lane, kr, chosen, cumG, T);
        kr -= cumG;
        thr = pfx | (unsigned int)chosen;
    }
    // thr = k-th largest key; kr = ties to select; T = total ties (uniform).

    if (kr == T) {
        // All threshold ties selected: pure >= mask from registers.
        #pragma unroll
        for (int i = 0; i < 2; ++i) {
            float4 o;
            o.x = (u[4*i+0] >= thr) ? 1.0f : 0.0f;
            o.y = (u[4*i+1] >= thr) ? 1.0f : 0.0f;
            o.z = (u[4*i+2] >= thr) ? 1.0f : 0.0f;
            o.w = (u[4*i+3] >= thr) ? 1.0f : 0.0f;
            outr4[(w << 7) + (i << 6) + lane] = o;
        }
    } else {
        // Rare: rank exact ties in ascending global index order.
        int eqtot = 0;
        #pragma unroll
        for (int j = 0; j < EPL; ++j) eqtot += (u[j] == thr) ? 1 : 0;
        int vv = eqtot;
        #pragma unroll
        for (int off = 1; off < 64; off <<= 1) {
            int t = __shfl_up(vv, off, 64);
            if (lane >= off) vv += t;
        }
        if (lane == 63) wtie[w] = vv;             // per-wave tie totals
        __syncthreads();
        int base = 0;
        #pragma unroll
        for (int ww = 0; ww < 8; ++ww) if (ww < w) base += wtie[ww];

        #pragma unroll
        for (int i = 0; i < 2; ++i) {
            const int e0 = (u[4*i+0] == thr) ? 1 : 0;
            const int e1 = (u[4*i+1] == thr) ? 1 : 0;
            const int e2 = (u[4*i+2] == thr) ? 1 : 0;
            const int e3 = (u[4*i+3] == thr) ? 1 : 0;
            const int ti = e0 + e1 + e2 + e3;
            int vi = ti;
            #pragma unroll
            for (int off = 1; off < 64; off <<= 1) {
                int t = __shfl_up(vi, off, 64);
                if (lane >= off) vi += t;
            }
            int r = base + (vi - ti);             // ties before my first one
            const int tot = __shfl(vi, 63, 64);   // wave ties in this i-group
            float4 o;
            o.x = (u[4*i+0] > thr) ? 1.0f : ((e0 && r < kr) ? 1.0f : 0.0f); r += e0;
            o.y = (u[4*i+1] > thr) ? 1.0f : ((e1 && r < kr) ? 1.0f : 0.0f); r += e1;
            o.z = (u[4*i+2] > thr) ? 1.0f : ((e2 && r < kr) ? 1.0f : 0.0f); r += e2;
            o.w = (u[4*i+3] > thr) ? 1.0f : ((e3 && r < kr) ? 1.0f : 0.0f); r += e3;
            outr4[(w << 7) + (i << 6) + lane] = o;
            base += tot;
        }
    }
}

extern "C" void kernel_launch(void* const* d_in, const int* in_sizes, int n_in,
                              void* d_out, int out_size, void* d_ws, size_t ws_size,
                              hipStream_t stream) {
    const float* x   = (const float*)d_in[0];
    // d_in[1] = k vector [bs] (unused: forward mask depends only on k0)
    const int*   k0  = (const int*)d_in[2];
    float*       out = (float*)d_out;

    const int bs = in_sizes[1];                   // dim == 4096 (reference)
    topk_mask_kernel<<<bs, 512, 0, stream>>>(x, k0, out);
}